// Round 1
// baseline (1247.473 us; speedup 1.0000x reference)
//
#include <hip/hip_runtime.h>
#include <hip/hip_bf16.h>
#include <math.h>

// Problem constants
#define BB 64
#define TT 128
#define VV 25
#define CC 128
#define KK 128
#define RR 32
#define TC 4  // timesteps per block in fused kernel

// Workspace layout (float offsets)
#define WS_XBAR 0              // [B,V,C]      204800
#define WS_PHIX 204800         // [B,V,K]      204800
#define WS_THX  409600         // [B,V,K]      204800
#define WS_HBAR 614400         // [B,V,K]      204800
#define WS_XQ   819200         // [B,V,K]      204800
#define WS_XK   1024000        // [B,V,K]      204800
#define WS_CA   1228800        // [B,K]        8192
#define WS_GATE 1236992        // [B,K]        8192
#define WS_AT   1245184        // [B,V,V,K]    5120000  (A_tilde transposed: [b][u][v][k])
// total 6,365,184 floats = 25.5 MB

// ---------------------------------------------------------------------------
// Kernel A: xbar[b,v,c] = mean_t x[b,t,v,c].  2 (b,v) rows per 64-thread block,
// float4 over c (32 lanes per row).
__global__ __launch_bounds__(64) void kA(const float* __restrict__ x, float* __restrict__ xbar) {
    int row = blockIdx.x * 2 + (threadIdx.x >> 5);   // b*V + v
    int cq  = threadIdx.x & 31;                      // float4 index over C=128
    int b = row / VV, v = row % VV;
    const float4* p = (const float4*)x + (size_t)b * TT * VV * (CC/4) + (size_t)v * (CC/4) + cq;
    float sx = 0.f, sy = 0.f, sz = 0.f, sw = 0.f;
    #pragma unroll 8
    for (int t = 0; t < TT; ++t) {
        float4 a = p[(size_t)t * VV * (CC/4)];
        sx += a.x; sy += a.y; sz += a.z; sw += a.w;
    }
    float4 o; o.x = sx*(1.f/TT); o.y = sy*(1.f/TT); o.z = sz*(1.f/TT); o.w = sw*(1.f/TT);
    ((float4*)xbar)[(size_t)row * (CC/4) + cq] = o;
}

// ---------------------------------------------------------------------------
// Kernel B1: per (b,v): phi_x / theta_x / Hbar rows from xbar.
__global__ __launch_bounds__(128) void kB1(const float* __restrict__ xbar,
        const float* __restrict__ pw, const float* __restrict__ pb,
        const float* __restrict__ tw, const float* __restrict__ tb,
        const float* __restrict__ xw, const float* __restrict__ xbias,
        float* __restrict__ phix, float* __restrict__ thx, float* __restrict__ hbar) {
    int bv = blockIdx.x;
    int k = threadIdx.x;
    __shared__ float xv[CC];
    xv[k] = xbar[(size_t)bv * CC + k];
    __syncthreads();
    float sp = pb[k], st = tb[k], sh = xbias[k];
    for (int c = 0; c < CC; ++c) {
        float xc = xv[c];
        sp = fmaf(xc, pw[c*KK + k], sp);
        st = fmaf(xc, tw[c*KK + k], st);
        sh = fmaf(xc, xw[c*KK + k], sh);
    }
    phix[(size_t)bv*KK + k] = sp;
    thx [(size_t)bv*KK + k] = st;
    hbar[(size_t)bv*KK + k] = sh;
}

// ---------------------------------------------------------------------------
// Kernel B2: A_tilde (stored [b][i][j][k]) = A[k,i,j] + lam*(tanh(phi_i-theta_j)@kappa_w + kappa_b)
__global__ __launch_bounds__(128) void kB2(const float* __restrict__ phix, const float* __restrict__ thx,
        const float* __restrict__ kw, const float* __restrict__ kb,
        const float* __restrict__ A, const float* __restrict__ lam,
        float* __restrict__ At) {
    int blk = blockIdx.x;               // b*V*V + i*V + j
    int b = blk / (VV*VV);
    int r = blk % (VV*VV);
    int i = r / VV, j = r % VV;
    int k = threadIdx.x;
    __shared__ float f[KK];
    f[k] = tanhf(phix[((size_t)b*VV + i)*KK + k] - thx[((size_t)b*VV + j)*KK + k]);
    __syncthreads();
    float s = kb[k];
    for (int c = 0; c < KK; ++c) s = fmaf(f[c], kw[c*KK + k], s);
    At[(((size_t)b*VV + i)*VV + j)*KK + k] = A[(k*VV + i)*VV + j] + lam[0] * s;
}

// ---------------------------------------------------------------------------
// Kernel B34: per (b,u): Zbar row (in LDS) then XQ/XK rows.
__global__ __launch_bounds__(128) void kB34(const float* __restrict__ At, const float* __restrict__ hbar,
        const float* __restrict__ qw, const float* __restrict__ qb,
        const float* __restrict__ kw, const float* __restrict__ kb,
        float* __restrict__ XQ, float* __restrict__ XK) {
    int bu = blockIdx.x;                // b*V + u
    int b = bu / VV;
    int k = threadIdx.x;
    __shared__ float zb[KK];
    const float* at = At + ((size_t)bu * VV) * KK + k;
    const float* hb = hbar + (size_t)b * VV * KK + k;
    float s = 0.f;
    #pragma unroll
    for (int v = 0; v < VV; ++v) s = fmaf(at[v*KK], hb[v*KK], s);
    zb[k] = s;
    __syncthreads();
    float q = qb[k], kk2 = kb[k];
    for (int c = 0; c < KK; ++c) {
        float z = zb[c];
        q   = fmaf(z, qw[c*KK + k], q);
        kk2 = fmaf(z, kw[c*KK + k], kk2);
    }
    XQ[(size_t)bu*KK + k] = q;
    XK[(size_t)bu*KK + k] = kk2;
}

// ---------------------------------------------------------------------------
// Kernel B5: per (b,k): softmax over v of outer(q,k)/sqrt(T); ca[b,k] = sum_v Hbar * mean_u A_att
__global__ __launch_bounds__(64) void kB5(const float* __restrict__ XQ, const float* __restrict__ XK,
        const float* __restrict__ hbar, float* __restrict__ ca) {
    int b = blockIdx.x >> 7;
    int k = blockIdx.x & 127;
    int tid = threadIdx.x;
    __shared__ float qv[VV], kv[VV], hv[VV], m[VV], dinv[VV];
    if (tid < VV) {
        qv[tid] = XQ[((size_t)b*VV + tid)*KK + k];
        kv[tid] = XK[((size_t)b*VV + tid)*KK + k];
        hv[tid] = hbar[((size_t)b*VV + tid)*KK + k];
    }
    __syncthreads();
    const float invs = 0.08838834764831845f;   // 1/sqrt(128)
    if (tid < VV) {
        float q = qv[tid];
        float mx = -1e30f;
        #pragma unroll
        for (int v = 0; v < VV; ++v) mx = fmaxf(mx, q * kv[v] * invs);
        float d = 0.f;
        #pragma unroll
        for (int v = 0; v < VV; ++v) d += expf(q * kv[v] * invs - mx);
        m[tid] = mx; dinv[tid] = 1.f / d;
    }
    __syncthreads();
    float contrib = 0.f;
    if (tid < VV) {
        float kkv = kv[tid];
        float s = 0.f;
        #pragma unroll
        for (int u = 0; u < VV; ++u) s += expf(qv[u] * kkv * invs - m[u]) * dinv[u];
        contrib = s * (1.f / VV) * hv[tid];
    }
    #pragma unroll
    for (int off = 32; off > 0; off >>= 1) contrib += __shfl_down(contrib, off);
    if (tid == 0) ca[(size_t)b*KK + k] = contrib;
}

// ---------------------------------------------------------------------------
// Kernel B6: per b: gate = sigmoid(gelu(LN(ca@ca1_w+ca1_b)) @ ca2_w + ca2_b)
__global__ __launch_bounds__(128) void kB6(const float* __restrict__ ca,
        const float* __restrict__ w1, const float* __restrict__ b1,
        const float* __restrict__ lw, const float* __restrict__ lb,
        const float* __restrict__ w2, const float* __restrict__ b2,
        float* __restrict__ gate) {
    int b = blockIdx.x;
    int tid = threadIdx.x;
    __shared__ float cas[KK], t1[RR], c1[RR];
    cas[tid] = ca[(size_t)b*KK + tid];
    __syncthreads();
    if (tid < RR) {
        float s = b1[tid];
        for (int c = 0; c < KK; ++c) s = fmaf(cas[c], w1[c*RR + tid], s);
        t1[tid] = s;
    }
    __syncthreads();
    if (tid < RR) {
        float mu = 0.f;
        #pragma unroll
        for (int j = 0; j < RR; ++j) mu += t1[j];
        mu *= (1.f / RR);
        float var = 0.f;
        #pragma unroll
        for (int j = 0; j < RR; ++j) { float d = t1[j] - mu; var = fmaf(d, d, var); }
        var *= (1.f / RR);
        float xn = (t1[tid] - mu) * rsqrtf(var + 1e-5f) * lw[tid] + lb[tid];
        c1[tid] = 0.5f * xn * (1.f + erff(xn * 0.70710678118654752f));   // exact gelu
    }
    __syncthreads();
    float g = b2[tid];
    #pragma unroll
    for (int r = 0; r < RR; ++r) g = fmaf(c1[r], w2[r*KK + tid], g);
    gate[(size_t)b*KK + tid] = 1.f / (1.f + expf(-g));
}

// ---------------------------------------------------------------------------
// Kernel C (fused): per block (b, 4 timesteps), 128 threads (thread = k).
//   H[tt,v,k] = x[b,t,v,:]@xi_w[:,k]+xi_b[k]   (x staged transposed in LDS, broadcast reads)
//   Z[tt,u,k] = sum_v At[b,u,v,k]*H[tt,v,k]    (4 FMA per At load — tt amortization)
//   out = LN_k(gate[b,k]*Z) * ln2_w + ln2_b
#define XPAD 28   // lds row pitch for transposed x: 16B-aligned float4 reads over v
__global__ __launch_bounds__(128) void kC(const float* __restrict__ x, const float* __restrict__ At,
        const float* __restrict__ xw, const float* __restrict__ xbias,
        const float* __restrict__ gate, const float* __restrict__ lw, const float* __restrict__ lb,
        float* __restrict__ out) {
    int b  = blockIdx.x / (TT / TC);
    int tc = blockIdx.x % (TT / TC);
    int t0 = tc * TC;
    int k = threadIdx.x;

    __shared__ float sx[TC * CC * XPAD];       // 57344 B; reused as Zs (needs 100*129=12900 floats)
    __shared__ float ms[TC * VV], rs[TC * VV];
    float* Zs = sx;

    // stage x[b, t0..t0+3] transposed: sx[tt][c][v]
    const float* xblk = x + (size_t)(b * TT + t0) * VV * CC;
    for (int tt = 0; tt < TC; ++tt) {
        const float* xg = xblk + tt * VV * CC;
        float* dst = sx + tt * CC * XPAD;
        for (int i = threadIdx.x; i < VV * CC; i += 128) {
            int v = i >> 7, c = i & 127;
            dst[c * XPAD + v] = xg[i];
        }
    }
    __syncthreads();

    // H phase: 100 accumulators per thread
    float h[TC][VV];
    {
        float bias = xbias[k];
        #pragma unroll
        for (int tt = 0; tt < TC; ++tt)
            #pragma unroll
            for (int v = 0; v < VV; ++v) h[tt][v] = bias;
    }
    #pragma unroll 2
    for (int c = 0; c < CC; ++c) {
        float w = xw[c * KK + k];
        #pragma unroll
        for (int tt = 0; tt < TC; ++tt) {
            const float* xc = sx + tt * CC * XPAD + c * XPAD;
            #pragma unroll
            for (int v4 = 0; v4 < 24; v4 += 4) {
                float4 a = *(const float4*)(xc + v4);
                h[tt][v4+0] = fmaf(a.x, w, h[tt][v4+0]);
                h[tt][v4+1] = fmaf(a.y, w, h[tt][v4+1]);
                h[tt][v4+2] = fmaf(a.z, w, h[tt][v4+2]);
                h[tt][v4+3] = fmaf(a.w, w, h[tt][v4+3]);
            }
            h[tt][24] = fmaf(xc[24], w, h[tt][24]);
        }
    }
    __syncthreads();   // all threads done reading sx; safe to overwrite with Zs

    // Z phase: graph conv + gate, write to LDS (row pitch 129 kills bank alignment issues)
    float g = gate[(size_t)b * KK + k];
    const float* Atb = At + (size_t)b * VV * VV * KK;
    #pragma unroll 1
    for (int u = 0; u < VV; ++u) {
        float z0 = 0.f, z1 = 0.f, z2 = 0.f, z3 = 0.f;
        #pragma unroll
        for (int v = 0; v < VV; ++v) {
            float a = Atb[(u * VV + v) * KK + k];
            z0 = fmaf(a, h[0][v], z0);
            z1 = fmaf(a, h[1][v], z1);
            z2 = fmaf(a, h[2][v], z2);
            z3 = fmaf(a, h[3][v], z3);
        }
        Zs[(0*VV + u) * 129 + k] = z0 * g;
        Zs[(1*VV + u) * 129 + k] = z1 * g;
        Zs[(2*VV + u) * 129 + k] = z2 * g;
        Zs[(3*VV + u) * 129 + k] = z3 * g;
    }
    __syncthreads();

    // LN stats: one thread per (tt,u) row (100 of 128 active); pitch 129 → conflict-free
    if (k < TC * VV) {
        float s = 0.f, s2 = 0.f;
        for (int i = 0; i < KK; ++i) {
            float v = Zs[k * 129 + i];
            s += v; s2 = fmaf(v, v, s2);
        }
        float mu = s * (1.f / KK);
        float var = s2 * (1.f / KK) - mu * mu;
        ms[k] = mu;
        rs[k] = rsqrtf(var + 1e-5f);
    }
    __syncthreads();

    // epilogue: normalize + affine, coalesced stores
    float w2 = lw[k], b2 = lb[k];
    float* ob = out + (size_t)(b * TT + t0) * VV * KK;
    #pragma unroll 1
    for (int row = 0; row < TC * VV; ++row) {
        float val = (Zs[row * 129 + k] - ms[row]) * rs[row] * w2 + b2;
        ob[(size_t)row * KK + k] = val;
    }
}

// ---------------------------------------------------------------------------
extern "C" void kernel_launch(void* const* d_in, const int* in_sizes, int n_in,
                              void* d_out, int out_size, void* d_ws, size_t ws_size,
                              hipStream_t stream) {
    const float* x      = (const float*)d_in[0];
    const float* A      = (const float*)d_in[1];
    const float* lam    = (const float*)d_in[2];
    const float* phi_w  = (const float*)d_in[3];
    const float* phi_b  = (const float*)d_in[4];
    const float* th_w   = (const float*)d_in[5];
    const float* th_b   = (const float*)d_in[6];
    const float* ka_w   = (const float*)d_in[7];
    const float* ka_b   = (const float*)d_in[8];
    const float* xi_w   = (const float*)d_in[9];
    const float* xi_b   = (const float*)d_in[10];
    const float* q_w    = (const float*)d_in[11];
    const float* q_b    = (const float*)d_in[12];
    const float* k_w    = (const float*)d_in[13];
    const float* k_b    = (const float*)d_in[14];
    const float* ca1_w  = (const float*)d_in[15];
    const float* ca1_b  = (const float*)d_in[16];
    const float* ln1_w  = (const float*)d_in[17];
    const float* ln1_b  = (const float*)d_in[18];
    const float* ca2_w  = (const float*)d_in[19];
    const float* ca2_b  = (const float*)d_in[20];
    const float* ln2_w  = (const float*)d_in[21];
    const float* ln2_b  = (const float*)d_in[22];
    float* out = (float*)d_out;
    float* ws  = (float*)d_ws;

    kA  <<<BB*VV/2, 64, 0, stream>>>(x, ws + WS_XBAR);
    kB1 <<<BB*VV, 128, 0, stream>>>(ws + WS_XBAR, phi_w, phi_b, th_w, th_b, xi_w, xi_b,
                                    ws + WS_PHIX, ws + WS_THX, ws + WS_HBAR);
    kB2 <<<BB*VV*VV, 128, 0, stream>>>(ws + WS_PHIX, ws + WS_THX, ka_w, ka_b, A, lam, ws + WS_AT);
    kB34<<<BB*VV, 128, 0, stream>>>(ws + WS_AT, ws + WS_HBAR, q_w, q_b, k_w, k_b,
                                    ws + WS_XQ, ws + WS_XK);
    kB5 <<<BB*KK, 64, 0, stream>>>(ws + WS_XQ, ws + WS_XK, ws + WS_HBAR, ws + WS_CA);
    kB6 <<<BB, 128, 0, stream>>>(ws + WS_CA, ca1_w, ca1_b, ln1_w, ln1_b, ca2_w, ca2_b, ws + WS_GATE);
    kC  <<<BB*(TT/TC), 128, 0, stream>>>(x, ws + WS_AT, xi_w, xi_b, ws + WS_GATE, ln2_w, ln2_b, out);
}

// Round 2
// 626.311 us; speedup vs baseline: 1.9918x; 1.9918x over previous
//
#include <hip/hip_runtime.h>
#include <hip/hip_bf16.h>
#include <math.h>

// Problem constants
#define BB 64
#define TT 128
#define VV 25
#define CC 128
#define KK 128
#define RR 32
#define TC 4   // timesteps per kZ block

typedef __attribute__((ext_vector_type(8))) short bf16x8;
typedef __attribute__((ext_vector_type(4))) float f32x4;

// bf16 helpers (RNE)
static __device__ __forceinline__ short f2bf(float f) {
    union { float f; unsigned u; } a; a.f = f;
    unsigned r = a.u + 0x7fffu + ((a.u >> 16) & 1u);
    return (short)(r >> 16);
}
static __device__ __forceinline__ float bf2f(short s) {
    union { unsigned u; float f; } a; a.u = ((unsigned)(unsigned short)s) << 16;
    return a.f;
}

// Workspace layout (float offsets)
#define WS_XBAR 0              // [B,V,C]      204800
#define WS_PHIX 204800         // [B,V,K]      204800
#define WS_THX  409600         // [B,V,K]      204800
#define WS_HBAR 614400         // [B,V,K]      204800
#define WS_XQ   819200         // [B,V,K]      204800
#define WS_XK   1024000        // [B,V,K]      204800
#define WS_CA   1228800        // [B,K]        8192
#define WS_GATE 1236992        // [B,K]        8192
#define WS_AT   1245184        // [B,V,V,K]    5120000 fp32  (A_tilde: [b][u][v][k])
#define WS_BT   6365184        // [K][C]       16384 bf16 = 8192 floats (xi_w transposed, bf16)
#define WS_H    6373376        // [B*T*V][K]   26214400 bf16 = 13107200 floats
// total ~19.5M floats = 78 MB

// ---------------------------------------------------------------------------
// Kernel A: xbar[b,v,c] = mean_t x[b,t,v,c]
__global__ __launch_bounds__(64) void kA(const float* __restrict__ x, float* __restrict__ xbar) {
    int row = blockIdx.x * 2 + (threadIdx.x >> 5);   // b*V + v
    int cq  = threadIdx.x & 31;
    int b = row / VV, v = row % VV;
    const float4* p = (const float4*)x + (size_t)b * TT * VV * (CC/4) + (size_t)v * (CC/4) + cq;
    float sx = 0.f, sy = 0.f, sz = 0.f, sw = 0.f;
    #pragma unroll 8
    for (int t = 0; t < TT; ++t) {
        float4 a = p[(size_t)t * VV * (CC/4)];
        sx += a.x; sy += a.y; sz += a.z; sw += a.w;
    }
    float4 o; o.x = sx*(1.f/TT); o.y = sy*(1.f/TT); o.z = sz*(1.f/TT); o.w = sw*(1.f/TT);
    ((float4*)xbar)[(size_t)row * (CC/4) + cq] = o;
}

// ---------------------------------------------------------------------------
// Kernel BT: BT[n][c] = bf16(xi_w[c][n])  (pre-transposed B operand for kH)
__global__ __launch_bounds__(256) void kBT(const float* __restrict__ xw, short* __restrict__ BT) {
    for (int i = threadIdx.x + blockIdx.x * 256; i < KK * CC; i += 256 * 64) {
        int n = i >> 7, c = i & 127;
        BT[i] = f2bf(xw[c * KK + n]);
    }
}

// ---------------------------------------------------------------------------
// Kernel B1: per (b,v): phi_x / theta_x / Hbar rows from xbar.
__global__ __launch_bounds__(128) void kB1(const float* __restrict__ xbar,
        const float* __restrict__ pw, const float* __restrict__ pb,
        const float* __restrict__ tw, const float* __restrict__ tb,
        const float* __restrict__ xw, const float* __restrict__ xbias,
        float* __restrict__ phix, float* __restrict__ thx, float* __restrict__ hbar) {
    int bv = blockIdx.x;
    int k = threadIdx.x;
    __shared__ float xv[CC];
    xv[k] = xbar[(size_t)bv * CC + k];
    __syncthreads();
    float sp = pb[k], st = tb[k], sh = xbias[k];
    for (int c = 0; c < CC; ++c) {
        float xc = xv[c];
        sp = fmaf(xc, pw[c*KK + k], sp);
        st = fmaf(xc, tw[c*KK + k], st);
        sh = fmaf(xc, xw[c*KK + k], sh);
    }
    phix[(size_t)bv*KK + k] = sp;
    thx [(size_t)bv*KK + k] = st;
    hbar[(size_t)bv*KK + k] = sh;
}

// ---------------------------------------------------------------------------
// Kernel B2 (rewritten): per (b,i) block: At[b,i,j,k] for all j.
// Stage f[j][k]=tanh(phi_i-theta_j) in LDS, read kappa_w ONCE per block.
__global__ __launch_bounds__(128) void kB2(const float* __restrict__ phix, const float* __restrict__ thx,
        const float* __restrict__ kw, const float* __restrict__ kb,
        const float* __restrict__ A, const float* __restrict__ lam,
        float* __restrict__ At) {
    int bi = blockIdx.x;                 // b*V + i
    int b = bi / VV, i = bi % VV;
    int k = threadIdx.x;
    __shared__ float f[VV][132];         // 13.2 KB, rows 16B-aligned
    float ph = phix[((size_t)b*VV + i)*KK + k];
    #pragma unroll 5
    for (int j = 0; j < VV; ++j)
        f[j][k] = tanhf(ph - thx[((size_t)b*VV + j)*KK + k]);
    __syncthreads();
    float s[VV];
    float bias = kb[k];
    #pragma unroll
    for (int j = 0; j < VV; ++j) s[j] = bias;
    #pragma unroll 2
    for (int c = 0; c < CC; c += 4) {
        float w0 = kw[(c+0)*KK + k];
        float w1 = kw[(c+1)*KK + k];
        float w2 = kw[(c+2)*KK + k];
        float w3 = kw[(c+3)*KK + k];
        #pragma unroll
        for (int j = 0; j < VV; ++j) {
            float4 fv = *(const float4*)&f[j][c];   // broadcast LDS read
            float t = fmaf(fv.x, w0, fmaf(fv.y, w1, fmaf(fv.z, w2, fv.w * w3)));
            s[j] += t;
        }
    }
    float l = lam[0];
    #pragma unroll 5
    for (int j = 0; j < VV; ++j)
        At[(((size_t)b*VV + i)*VV + j)*KK + k] = A[((size_t)k*VV + i)*VV + j] + l * s[j];
}

// ---------------------------------------------------------------------------
// Kernel B34: per (b,u): Zbar row (in LDS) then XQ/XK rows.
__global__ __launch_bounds__(128) void kB34(const float* __restrict__ At, const float* __restrict__ hbar,
        const float* __restrict__ qw, const float* __restrict__ qb,
        const float* __restrict__ kw, const float* __restrict__ kb,
        float* __restrict__ XQ, float* __restrict__ XK) {
    int bu = blockIdx.x;
    int b = bu / VV;
    int k = threadIdx.x;
    __shared__ float zb[KK];
    const float* at = At + ((size_t)bu * VV) * KK + k;
    const float* hb = hbar + (size_t)b * VV * KK + k;
    float s = 0.f;
    #pragma unroll
    for (int v = 0; v < VV; ++v) s = fmaf(at[v*KK], hb[v*KK], s);
    zb[k] = s;
    __syncthreads();
    float q = qb[k], kk2 = kb[k];
    for (int c = 0; c < CC; ++c) {
        float z = zb[c];
        q   = fmaf(z, qw[c*KK + k], q);
        kk2 = fmaf(z, kw[c*KK + k], kk2);
    }
    XQ[(size_t)bu*KK + k] = q;
    XK[(size_t)bu*KK + k] = kk2;
}

// ---------------------------------------------------------------------------
// Kernel B5: ca[b,k] = sum_v Hbar * mean_u softmax_v(q_u k_v / sqrt(T))
__global__ __launch_bounds__(64) void kB5(const float* __restrict__ XQ, const float* __restrict__ XK,
        const float* __restrict__ hbar, float* __restrict__ ca) {
    int b = blockIdx.x >> 7;
    int k = blockIdx.x & 127;
    int tid = threadIdx.x;
    __shared__ float qv[VV], kv[VV], hv[VV], m[VV], dinv[VV];
    if (tid < VV) {
        qv[tid] = XQ[((size_t)b*VV + tid)*KK + k];
        kv[tid] = XK[((size_t)b*VV + tid)*KK + k];
        hv[tid] = hbar[((size_t)b*VV + tid)*KK + k];
    }
    __syncthreads();
    const float invs = 0.08838834764831845f;   // 1/sqrt(128)
    if (tid < VV) {
        float q = qv[tid];
        float mx = -1e30f;
        #pragma unroll
        for (int v = 0; v < VV; ++v) mx = fmaxf(mx, q * kv[v] * invs);
        float d = 0.f;
        #pragma unroll
        for (int v = 0; v < VV; ++v) d += expf(q * kv[v] * invs - mx);
        m[tid] = mx; dinv[tid] = 1.f / d;
    }
    __syncthreads();
    float contrib = 0.f;
    if (tid < VV) {
        float kkv = kv[tid];
        float s = 0.f;
        #pragma unroll
        for (int u = 0; u < VV; ++u) s += expf(qv[u] * kkv * invs - m[u]) * dinv[u];
        contrib = s * (1.f / VV) * hv[tid];
    }
    #pragma unroll
    for (int off = 32; off > 0; off >>= 1) contrib += __shfl_down(contrib, off);
    if (tid == 0) ca[(size_t)b*KK + k] = contrib;
}

// ---------------------------------------------------------------------------
// Kernel B6: gate = sigmoid(gelu(LN(ca@ca1_w+ca1_b)) @ ca2_w + ca2_b)
__global__ __launch_bounds__(128) void kB6(const float* __restrict__ ca,
        const float* __restrict__ w1, const float* __restrict__ b1,
        const float* __restrict__ lw, const float* __restrict__ lb,
        const float* __restrict__ w2, const float* __restrict__ b2,
        float* __restrict__ gate) {
    int b = blockIdx.x;
    int tid = threadIdx.x;
    __shared__ float cas[KK], t1[RR], c1[RR];
    cas[tid] = ca[(size_t)b*KK + tid];
    __syncthreads();
    if (tid < RR) {
        float s = b1[tid];
        for (int c = 0; c < KK; ++c) s = fmaf(cas[c], w1[c*RR + tid], s);
        t1[tid] = s;
    }
    __syncthreads();
    if (tid < RR) {
        float mu = 0.f;
        #pragma unroll
        for (int j = 0; j < RR; ++j) mu += t1[j];
        mu *= (1.f / RR);
        float var = 0.f;
        #pragma unroll
        for (int j = 0; j < RR; ++j) { float d = t1[j] - mu; var = fmaf(d, d, var); }
        var *= (1.f / RR);
        float xn = (t1[tid] - mu) * rsqrtf(var + 1e-5f) * lw[tid] + lb[tid];
        c1[tid] = 0.5f * xn * (1.f + erff(xn * 0.70710678118654752f));
    }
    __syncthreads();
    float g = b2[tid];
    #pragma unroll
    for (int r = 0; r < RR; ++r) g = fmaf(c1[r], w2[r*KK + tid], g);
    gate[(size_t)b*KK + tid] = 1.f / (1.f + expf(-g));
}

// ---------------------------------------------------------------------------
// Kernel H: bf16 MFMA GEMM.  H[m][n] = bf16( x[m][:] @ xi_w[:][n] + xi_b[n] )
// M = B*T*V = 204800 rows, K=C=128, N=K=128.  No LDS: A frags converted from
// global fp32 x; B frags are dwordx4 loads from pre-transposed bf16 BT (L2-hot).
// Block = 256 thr (4 waves), M-tile 128 (32 rows/wave = 2 row-tiles), N full.
__global__ __launch_bounds__(256) void kH(const float* __restrict__ x,
        const short* __restrict__ BT, const float* __restrict__ xbias,
        short* __restrict__ H) {
    int wave = threadIdx.x >> 6;
    int lane = threadIdx.x & 63;
    int l15 = lane & 15, quad = lane >> 4;
    size_t rowbase = (size_t)blockIdx.x * 128 + wave * 32;

    f32x4 acc[2][8];
    #pragma unroll
    for (int rt = 0; rt < 2; ++rt)
        #pragma unroll
        for (int ct = 0; ct < 8; ++ct)
            acc[rt][ct] = (f32x4){0.f, 0.f, 0.f, 0.f};

    #pragma unroll
    for (int s = 0; s < 4; ++s) {              // K-steps of 32
        bf16x8 afr[2];
        #pragma unroll
        for (int rt = 0; rt < 2; ++rt) {
            const float* ap = x + (rowbase + rt*16 + l15) * CC + s*32 + quad*8;
            float4 a0 = *(const float4*)ap;
            float4 a1 = *(const float4*)(ap + 4);
            union { bf16x8 v; short h[8]; } u;
            u.h[0] = f2bf(a0.x); u.h[1] = f2bf(a0.y); u.h[2] = f2bf(a0.z); u.h[3] = f2bf(a0.w);
            u.h[4] = f2bf(a1.x); u.h[5] = f2bf(a1.y); u.h[6] = f2bf(a1.z); u.h[7] = f2bf(a1.w);
            afr[rt] = u.v;
        }
        #pragma unroll
        for (int ct = 0; ct < 8; ++ct) {
            bf16x8 bfr = *(const bf16x8*)(BT + (ct*16 + l15) * CC + s*32 + quad*8);
            acc[0][ct] = __builtin_amdgcn_mfma_f32_16x16x32_bf16(afr[0], bfr, acc[0][ct], 0, 0, 0);
            acc[1][ct] = __builtin_amdgcn_mfma_f32_16x16x32_bf16(afr[1], bfr, acc[1][ct], 0, 0, 0);
        }
    }
    // store: D elem (reg i, lane): row = rowbase+rt*16+quad*4+i, col = ct*16+l15
    #pragma unroll
    for (int ct = 0; ct < 8; ++ct) {
        float bias = xbias[ct*16 + l15];
        #pragma unroll
        for (int rt = 0; rt < 2; ++rt) {
            size_t row = rowbase + rt*16 + quad*4;
            #pragma unroll
            for (int i = 0; i < 4; ++i)
                H[(row + i) * KK + ct*16 + l15] = f2bf(acc[rt][ct][i] + bias);
        }
    }
}

// ---------------------------------------------------------------------------
// Kernel Z: per block (b, 4 timesteps), 128 threads (thread = k).
//   h[tt][v] from global bf16 H (registers);
//   z[tt,u,k] = gate * sum_v At[b,u,v,k] h[tt][v]  → bf16 LDS (pitch 130);
//   LN over k per (tt,u) row; coalesced fp32 stores.
__global__ __launch_bounds__(128) void kZ(const short* __restrict__ H, const float* __restrict__ At,
        const float* __restrict__ gate, const float* __restrict__ lw, const float* __restrict__ lb,
        float* __restrict__ out) {
    int b  = blockIdx.x / (TT / TC);
    int tc = blockIdx.x % (TT / TC);
    int t0 = tc * TC;
    int k = threadIdx.x;

    __shared__ short Zs[TC * VV * 130];        // 26 KB
    __shared__ float ms[TC * VV], rs[TC * VV];

    // load H tile into registers
    const short* hb = H + ((size_t)(b * TT + t0) * VV) * KK + k;
    float h[TC][VV];
    #pragma unroll
    for (int tt = 0; tt < TC; ++tt)
        #pragma unroll
        for (int v = 0; v < VV; ++v)
            h[tt][v] = bf2f(hb[(tt * VV + v) * KK]);

    float g = gate[(size_t)b * KK + k];
    const float* Atb = At + (size_t)b * VV * VV * KK + k;
    #pragma unroll 1
    for (int u = 0; u < VV; ++u) {
        float z0 = 0.f, z1 = 0.f, z2 = 0.f, z3 = 0.f;
        #pragma unroll
        for (int v = 0; v < VV; ++v) {
            float a = Atb[(u * VV + v) * KK];
            z0 = fmaf(a, h[0][v], z0);
            z1 = fmaf(a, h[1][v], z1);
            z2 = fmaf(a, h[2][v], z2);
            z3 = fmaf(a, h[3][v], z3);
        }
        Zs[(0*VV + u) * 130 + k] = f2bf(z0 * g);
        Zs[(1*VV + u) * 130 + k] = f2bf(z1 * g);
        Zs[(2*VV + u) * 130 + k] = f2bf(z2 * g);
        Zs[(3*VV + u) * 130 + k] = f2bf(z3 * g);
    }
    __syncthreads();

    // LN stats: thread r < 100 reduces row r
    if (k < TC * VV) {
        float s = 0.f, s2 = 0.f;
        #pragma unroll 4
        for (int i = 0; i < KK; ++i) {
            float v = bf2f(Zs[k * 130 + i]);
            s += v; s2 = fmaf(v, v, s2);
        }
        float mu = s * (1.f / KK);
        float var = s2 * (1.f / KK) - mu * mu;
        ms[k] = mu;
        rs[k] = rsqrtf(var + 1e-5f);
    }
    __syncthreads();

    float w2 = lw[k], b2 = lb[k];
    float* ob = out + ((size_t)(b * TT + t0) * VV) * KK;
    #pragma unroll 1
    for (int row = 0; row < TC * VV; ++row) {
        float val = (bf2f(Zs[row * 130 + k]) - ms[row]) * rs[row] * w2 + b2;
        ob[(size_t)row * KK + k] = val;
    }
}

// ---------------------------------------------------------------------------
extern "C" void kernel_launch(void* const* d_in, const int* in_sizes, int n_in,
                              void* d_out, int out_size, void* d_ws, size_t ws_size,
                              hipStream_t stream) {
    const float* x      = (const float*)d_in[0];
    const float* A      = (const float*)d_in[1];
    const float* lam    = (const float*)d_in[2];
    const float* phi_w  = (const float*)d_in[3];
    const float* phi_b  = (const float*)d_in[4];
    const float* th_w   = (const float*)d_in[5];
    const float* th_b   = (const float*)d_in[6];
    const float* ka_w   = (const float*)d_in[7];
    const float* ka_b   = (const float*)d_in[8];
    const float* xi_w   = (const float*)d_in[9];
    const float* xi_b   = (const float*)d_in[10];
    const float* q_w    = (const float*)d_in[11];
    const float* q_b    = (const float*)d_in[12];
    const float* k_w    = (const float*)d_in[13];
    const float* k_b    = (const float*)d_in[14];
    const float* ca1_w  = (const float*)d_in[15];
    const float* ca1_b  = (const float*)d_in[16];
    const float* ln1_w  = (const float*)d_in[17];
    const float* ln1_b  = (const float*)d_in[18];
    const float* ca2_w  = (const float*)d_in[19];
    const float* ca2_b  = (const float*)d_in[20];
    const float* ln2_w  = (const float*)d_in[21];
    const float* ln2_b  = (const float*)d_in[22];
    float* out = (float*)d_out;
    float* ws  = (float*)d_ws;
    short* BT  = (short*)(ws + WS_BT);
    short* H   = (short*)(ws + WS_H);

    kBT <<<64, 256, 0, stream>>>(xi_w, BT);
    kA  <<<BB*VV/2, 64, 0, stream>>>(x, ws + WS_XBAR);
    kH  <<<(BB*TT*VV)/128, 256, 0, stream>>>(x, BT, xi_b, H);
    kB1 <<<BB*VV, 128, 0, stream>>>(ws + WS_XBAR, phi_w, phi_b, th_w, th_b, xi_w, xi_b,
                                    ws + WS_PHIX, ws + WS_THX, ws + WS_HBAR);
    kB2 <<<BB*VV, 128, 0, stream>>>(ws + WS_PHIX, ws + WS_THX, ka_w, ka_b, A, lam, ws + WS_AT);
    kB34<<<BB*VV, 128, 0, stream>>>(ws + WS_AT, ws + WS_HBAR, q_w, q_b, k_w, k_b,
                                    ws + WS_XQ, ws + WS_XK);
    kB5 <<<BB*KK, 64, 0, stream>>>(ws + WS_XQ, ws + WS_XK, ws + WS_HBAR, ws + WS_CA);
    kB6 <<<BB, 128, 0, stream>>>(ws + WS_CA, ca1_w, ca1_b, ln1_w, ln1_b, ca2_w, ca2_b, ws + WS_GATE);
    kZ  <<<BB*(TT/TC), 128, 0, stream>>>(H, ws + WS_AT, ws + WS_GATE, ln2_w, ln2_b, out);
}

// Round 3
// 570.326 us; speedup vs baseline: 2.1873x; 1.0982x over previous
//
#include <hip/hip_runtime.h>
#include <hip/hip_bf16.h>
#include <math.h>

// Problem constants
#define BB 64
#define TT 128
#define VV 25
#define CC 128
#define KK 128
#define RR 32
#define TC 4   // timesteps per kZ block
#define USP 5  // u-rows per kZ block (VV = 5 * USP)

typedef __attribute__((ext_vector_type(8))) short bf16x8;
typedef __attribute__((ext_vector_type(4))) float f32x4;

// bf16 helpers (RNE)
static __device__ __forceinline__ short f2bf(float f) {
    union { float f; unsigned u; } a; a.f = f;
    unsigned r = a.u + 0x7fffu + ((a.u >> 16) & 1u);
    return (short)(r >> 16);
}
static __device__ __forceinline__ float bf2f(short s) {
    union { unsigned u; float f; } a; a.u = ((unsigned)(unsigned short)s) << 16;
    return a.f;
}

// Workspace layout (float offsets)
#define WS_XBAR 0              // [B,V,C]      204800
#define WS_PHIX 204800         // [B,V,K]      204800
#define WS_THX  409600         // [B,V,K]      204800
#define WS_HBAR 614400         // [B,V,K]      204800
#define WS_XQ   819200         // [B,V,K]      204800
#define WS_XK   1024000        // [B,V,K]      204800
#define WS_CA   1228800        // [B,K]        8192
#define WS_GATE 1236992        // [B,K]        8192
#define WS_AT   1245184        // [B,V,V,K]    bf16 At: 5.12M shorts = 2.56M floats
#define WS_BT   6365184        // [K][C]       16384 bf16 (xi_w transposed)
#define WS_H    6373376        // [B*T*V][K]   26214400 bf16 = 13107200 floats
// total ~19.5M floats = 78 MB (At region reused, now half-occupied)

// ---------------------------------------------------------------------------
// Kernel A: xbar[b,v,c] = mean_t x[b,t,v,c].  One 256-thr block per (b,v) row:
// thread = (tq 0..7, cq 0..31), 16 timesteps each, LDS tree reduce.
__global__ __launch_bounds__(256) void kA(const float* __restrict__ x, float* __restrict__ xbar) {
    int row = blockIdx.x;                 // b*V + v
    int b = row / VV, v = row % VV;
    int tq = threadIdx.x >> 5, cq = threadIdx.x & 31;
    const float4* x4 = (const float4*)x;
    size_t base = ((size_t)b * TT * VV + v) * 32 + cq;
    float sx = 0.f, sy = 0.f, sz = 0.f, sw = 0.f;
    #pragma unroll 4
    for (int i = 0; i < 16; ++i) {
        float4 a = x4[base + (size_t)(tq * 16 + i) * VV * 32];
        sx += a.x; sy += a.y; sz += a.z; sw += a.w;
    }
    __shared__ float4 red[8][32];
    red[tq][cq] = (float4){sx, sy, sz, sw};
    __syncthreads();
    if (tq == 0) {
        float4 o = red[0][cq];
        #pragma unroll
        for (int j = 1; j < 8; ++j) {
            float4 a = red[j][cq];
            o.x += a.x; o.y += a.y; o.z += a.z; o.w += a.w;
        }
        o.x *= (1.f/TT); o.y *= (1.f/TT); o.z *= (1.f/TT); o.w *= (1.f/TT);
        ((float4*)xbar)[(size_t)row * 32 + cq] = o;
    }
}

// ---------------------------------------------------------------------------
// Kernel BT: BT[n][c] = bf16(xi_w[c][n])  (pre-transposed B operand for kH)
__global__ __launch_bounds__(256) void kBT(const float* __restrict__ xw, short* __restrict__ BT) {
    for (int i = threadIdx.x + blockIdx.x * 256; i < KK * CC; i += 256 * 64) {
        int n = i >> 7, c = i & 127;
        BT[i] = f2bf(xw[c * KK + n]);
    }
}

// ---------------------------------------------------------------------------
// Kernel B1: per (b,v): phi_x / theta_x / Hbar rows from xbar.
__global__ __launch_bounds__(128) void kB1(const float* __restrict__ xbar,
        const float* __restrict__ pw, const float* __restrict__ pb,
        const float* __restrict__ tw, const float* __restrict__ tb,
        const float* __restrict__ xw, const float* __restrict__ xbias,
        float* __restrict__ phix, float* __restrict__ thx, float* __restrict__ hbar) {
    int bv = blockIdx.x;
    int k = threadIdx.x;
    __shared__ float xv[CC];
    xv[k] = xbar[(size_t)bv * CC + k];
    __syncthreads();
    float sp = pb[k], st = tb[k], sh = xbias[k];
    for (int c = 0; c < CC; ++c) {
        float xc = xv[c];
        sp = fmaf(xc, pw[c*KK + k], sp);
        st = fmaf(xc, tw[c*KK + k], st);
        sh = fmaf(xc, xw[c*KK + k], sh);
    }
    phix[(size_t)bv*KK + k] = sp;
    thx [(size_t)bv*KK + k] = st;
    hbar[(size_t)bv*KK + k] = sh;
}

// ---------------------------------------------------------------------------
// Kernel B2: per (b,i) block: At16[b,i,j,k] (bf16) for all j.
// Stage f[j][k]=tanh(phi_i-theta_j) in LDS, read kappa_w ONCE per block.
__global__ __launch_bounds__(128) void kB2(const float* __restrict__ phix, const float* __restrict__ thx,
        const float* __restrict__ kw, const float* __restrict__ kb,
        const float* __restrict__ A, const float* __restrict__ lam,
        short* __restrict__ At16) {
    int bi = blockIdx.x;                 // b*V + i
    int b = bi / VV, i = bi % VV;
    int k = threadIdx.x;
    __shared__ float f[VV][132];
    float ph = phix[((size_t)b*VV + i)*KK + k];
    #pragma unroll 5
    for (int j = 0; j < VV; ++j)
        f[j][k] = tanhf(ph - thx[((size_t)b*VV + j)*KK + k]);
    __syncthreads();
    float s[VV];
    float bias = kb[k];
    #pragma unroll
    for (int j = 0; j < VV; ++j) s[j] = bias;
    #pragma unroll 2
    for (int c = 0; c < CC; c += 4) {
        float w0 = kw[(c+0)*KK + k];
        float w1 = kw[(c+1)*KK + k];
        float w2 = kw[(c+2)*KK + k];
        float w3 = kw[(c+3)*KK + k];
        #pragma unroll
        for (int j = 0; j < VV; ++j) {
            float4 fv = *(const float4*)&f[j][c];   // broadcast LDS read
            float t = fmaf(fv.x, w0, fmaf(fv.y, w1, fmaf(fv.z, w2, fv.w * w3)));
            s[j] += t;
        }
    }
    float l = lam[0];
    #pragma unroll 5
    for (int j = 0; j < VV; ++j)
        At16[(((size_t)b*VV + i)*VV + j)*KK + k] = f2bf(A[((size_t)k*VV + i)*VV + j] + l * s[j]);
}

// ---------------------------------------------------------------------------
// Kernel B34: per (b,u): Zbar row (in LDS) then XQ/XK rows.  At in bf16 now.
__global__ __launch_bounds__(128) void kB34(const short* __restrict__ At16, const float* __restrict__ hbar,
        const float* __restrict__ qw, const float* __restrict__ qb,
        const float* __restrict__ kw, const float* __restrict__ kb,
        float* __restrict__ XQ, float* __restrict__ XK) {
    int bu = blockIdx.x;
    int b = bu / VV;
    int k = threadIdx.x;
    __shared__ float zb[KK];
    const short* at = At16 + ((size_t)bu * VV) * KK + k;
    const float* hb = hbar + (size_t)b * VV * KK + k;
    float s = 0.f;
    #pragma unroll
    for (int v = 0; v < VV; ++v) s = fmaf(bf2f(at[v*KK]), hb[v*KK], s);
    zb[k] = s;
    __syncthreads();
    float q = qb[k], kk2 = kb[k];
    for (int c = 0; c < CC; ++c) {
        float z = zb[c];
        q   = fmaf(z, qw[c*KK + k], q);
        kk2 = fmaf(z, kw[c*KK + k], kk2);
    }
    XQ[(size_t)bu*KK + k] = q;
    XK[(size_t)bu*KK + k] = kk2;
}

// ---------------------------------------------------------------------------
// Kernel B5: ca[b,k] = sum_v Hbar * mean_u softmax_v(q_u k_v / sqrt(T))
__global__ __launch_bounds__(64) void kB5(const float* __restrict__ XQ, const float* __restrict__ XK,
        const float* __restrict__ hbar, float* __restrict__ ca) {
    int b = blockIdx.x >> 7;
    int k = blockIdx.x & 127;
    int tid = threadIdx.x;
    __shared__ float qv[VV], kv[VV], hv[VV], m[VV], dinv[VV];
    if (tid < VV) {
        qv[tid] = XQ[((size_t)b*VV + tid)*KK + k];
        kv[tid] = XK[((size_t)b*VV + tid)*KK + k];
        hv[tid] = hbar[((size_t)b*VV + tid)*KK + k];
    }
    __syncthreads();
    const float invs = 0.08838834764831845f;   // 1/sqrt(128)
    if (tid < VV) {
        float q = qv[tid];
        float mx = -1e30f;
        #pragma unroll
        for (int v = 0; v < VV; ++v) mx = fmaxf(mx, q * kv[v] * invs);
        float d = 0.f;
        #pragma unroll
        for (int v = 0; v < VV; ++v) d += expf(q * kv[v] * invs - mx);
        m[tid] = mx; dinv[tid] = 1.f / d;
    }
    __syncthreads();
    float contrib = 0.f;
    if (tid < VV) {
        float kkv = kv[tid];
        float s = 0.f;
        #pragma unroll
        for (int u = 0; u < VV; ++u) s += expf(qv[u] * kkv * invs - m[u]) * dinv[u];
        contrib = s * (1.f / VV) * hv[tid];
    }
    #pragma unroll
    for (int off = 32; off > 0; off >>= 1) contrib += __shfl_down(contrib, off);
    if (tid == 0) ca[(size_t)b*KK + k] = contrib;
}

// ---------------------------------------------------------------------------
// Kernel B6: gate = sigmoid(gelu(LN(ca@ca1_w+ca1_b)) @ ca2_w + ca2_b)
__global__ __launch_bounds__(128) void kB6(const float* __restrict__ ca,
        const float* __restrict__ w1, const float* __restrict__ b1,
        const float* __restrict__ lw, const float* __restrict__ lb,
        const float* __restrict__ w2, const float* __restrict__ b2,
        float* __restrict__ gate) {
    int b = blockIdx.x;
    int tid = threadIdx.x;
    __shared__ float cas[KK], t1[RR], c1[RR];
    cas[tid] = ca[(size_t)b*KK + tid];
    __syncthreads();
    if (tid < RR) {
        float s = b1[tid];
        for (int c = 0; c < KK; ++c) s = fmaf(cas[c], w1[c*RR + tid], s);
        t1[tid] = s;
    }
    __syncthreads();
    if (tid < RR) {
        float mu = 0.f;
        #pragma unroll
        for (int j = 0; j < RR; ++j) mu += t1[j];
        mu *= (1.f / RR);
        float var = 0.f;
        #pragma unroll
        for (int j = 0; j < RR; ++j) { float d = t1[j] - mu; var = fmaf(d, d, var); }
        var *= (1.f / RR);
        float xn = (t1[tid] - mu) * rsqrtf(var + 1e-5f) * lw[tid] + lb[tid];
        c1[tid] = 0.5f * xn * (1.f + erff(xn * 0.70710678118654752f));
    }
    __syncthreads();
    float g = b2[tid];
    #pragma unroll
    for (int r = 0; r < RR; ++r) g = fmaf(c1[r], w2[r*KK + tid], g);
    gate[(size_t)b*KK + tid] = 1.f / (1.f + expf(-g));
}

// ---------------------------------------------------------------------------
// Kernel H: bf16 MFMA GEMM.  H[m][n] = bf16( x[m][:] @ xi_w[:][n] + xi_b[n] )
__global__ __launch_bounds__(256) void kH(const float* __restrict__ x,
        const short* __restrict__ BT, const float* __restrict__ xbias,
        short* __restrict__ H) {
    int wave = threadIdx.x >> 6;
    int lane = threadIdx.x & 63;
    int l15 = lane & 15, quad = lane >> 4;
    size_t rowbase = (size_t)blockIdx.x * 128 + wave * 32;

    f32x4 acc[2][8];
    #pragma unroll
    for (int rt = 0; rt < 2; ++rt)
        #pragma unroll
        for (int ct = 0; ct < 8; ++ct)
            acc[rt][ct] = (f32x4){0.f, 0.f, 0.f, 0.f};

    #pragma unroll
    for (int s = 0; s < 4; ++s) {              // K-steps of 32
        bf16x8 afr[2];
        #pragma unroll
        for (int rt = 0; rt < 2; ++rt) {
            const float* ap = x + (rowbase + rt*16 + l15) * CC + s*32 + quad*8;
            float4 a0 = *(const float4*)ap;
            float4 a1 = *(const float4*)(ap + 4);
            union { bf16x8 v; short h[8]; } u;
            u.h[0] = f2bf(a0.x); u.h[1] = f2bf(a0.y); u.h[2] = f2bf(a0.z); u.h[3] = f2bf(a0.w);
            u.h[4] = f2bf(a1.x); u.h[5] = f2bf(a1.y); u.h[6] = f2bf(a1.z); u.h[7] = f2bf(a1.w);
            afr[rt] = u.v;
        }
        #pragma unroll
        for (int ct = 0; ct < 8; ++ct) {
            bf16x8 bfr = *(const bf16x8*)(BT + (ct*16 + l15) * CC + s*32 + quad*8);
            acc[0][ct] = __builtin_amdgcn_mfma_f32_16x16x32_bf16(afr[0], bfr, acc[0][ct], 0, 0, 0);
            acc[1][ct] = __builtin_amdgcn_mfma_f32_16x16x32_bf16(afr[1], bfr, acc[1][ct], 0, 0, 0);
        }
    }
    #pragma unroll
    for (int ct = 0; ct < 8; ++ct) {
        float bias = xbias[ct*16 + l15];
        #pragma unroll
        for (int rt = 0; rt < 2; ++rt) {
            size_t row = rowbase + rt*16 + quad*4;
            #pragma unroll
            for (int i = 0; i < 4; ++i)
                H[(row + i) * KK + ct*16 + l15] = f2bf(acc[rt][ct][i] + bias);
        }
    }
}

// ---------------------------------------------------------------------------
// Kernel Z: per block (b, 4 timesteps, 5 u-rows), 128 threads (thread = k).
//   h[tt][v] from global bf16 H; z = gate * sum_v At16 h → bf16 LDS (pitch 132);
//   LN over k per (tt,u) row; coalesced fp32 stores.
__global__ __launch_bounds__(128, 3) void kZ(const short* __restrict__ H, const short* __restrict__ At16,
        const float* __restrict__ gate, const float* __restrict__ lw, const float* __restrict__ lb,
        float* __restrict__ out) {
    int bz = blockIdx.x;
    int uz = bz % USP;
    int tc = (bz / USP) % (TT / TC);
    int b  = bz / (USP * (TT / TC));
    int t0 = tc * TC, u0 = uz * USP;
    int k = threadIdx.x;

    __shared__ short Zs[TC * USP * 132];       // 5.28 KB
    __shared__ float ms[TC * USP], rs[TC * USP];

    // load H tile into registers (100 bf16 scalars, k-coalesced across wave)
    const short* hb = H + ((size_t)(b * TT + t0) * VV) * KK + k;
    float h[TC][VV];
    #pragma unroll
    for (int tt = 0; tt < TC; ++tt)
        #pragma unroll
        for (int v = 0; v < VV; ++v)
            h[tt][v] = bf2f(hb[(tt * VV + v) * KK]);

    float g = gate[(size_t)b * KK + k];
    const short* atb = At16 + (((size_t)b * VV + u0) * VV) * KK + k;
    #pragma unroll 1
    for (int uu = 0; uu < USP; ++uu) {
        float z0 = 0.f, z1 = 0.f, z2 = 0.f, z3 = 0.f;
        #pragma unroll
        for (int v = 0; v < VV; ++v) {
            float a = bf2f(atb[(uu * VV + v) * KK]);
            z0 = fmaf(a, h[0][v], z0);
            z1 = fmaf(a, h[1][v], z1);
            z2 = fmaf(a, h[2][v], z2);
            z3 = fmaf(a, h[3][v], z3);
        }
        Zs[(0*USP + uu) * 132 + k] = f2bf(z0 * g);
        Zs[(1*USP + uu) * 132 + k] = f2bf(z1 * g);
        Zs[(2*USP + uu) * 132 + k] = f2bf(z2 * g);
        Zs[(3*USP + uu) * 132 + k] = f2bf(z3 * g);
    }
    __syncthreads();

    // LN stats: thread r < 20 reduces row r (short4 reads, 8B-aligned: pitch 132)
    if (k < TC * USP) {
        const short4* zr = (const short4*)(Zs + k * 132);
        float s = 0.f, s2 = 0.f;
        #pragma unroll 8
        for (int i = 0; i < KK/4; ++i) {
            short4 q = zr[i];
            float a = bf2f(q.x), bq = bf2f(q.y), c = bf2f(q.z), d = bf2f(q.w);
            s += a + bq + c + d;
            s2 = fmaf(a, a, fmaf(bq, bq, fmaf(c, c, fmaf(d, d, s2))));
        }
        float mu = s * (1.f / KK);
        float var = s2 * (1.f / KK) - mu * mu;
        ms[k] = mu;
        rs[k] = rsqrtf(var + 1e-5f);
    }
    __syncthreads();

    float w2 = lw[k], b2v = lb[k];
    #pragma unroll
    for (int r = 0; r < TC * USP; ++r) {
        int tt = r / USP, uu = r % USP;
        float val = (bf2f(Zs[r * 132 + k]) - ms[r]) * rs[r] * w2 + b2v;
        out[(((size_t)(b * TT + t0 + tt)) * VV + (u0 + uu)) * KK + k] = val;
    }
}

// ---------------------------------------------------------------------------
extern "C" void kernel_launch(void* const* d_in, const int* in_sizes, int n_in,
                              void* d_out, int out_size, void* d_ws, size_t ws_size,
                              hipStream_t stream) {
    const float* x      = (const float*)d_in[0];
    const float* A      = (const float*)d_in[1];
    const float* lam    = (const float*)d_in[2];
    const float* phi_w  = (const float*)d_in[3];
    const float* phi_b  = (const float*)d_in[4];
    const float* th_w   = (const float*)d_in[5];
    const float* th_b   = (const float*)d_in[6];
    const float* ka_w   = (const float*)d_in[7];
    const float* ka_b   = (const float*)d_in[8];
    const float* xi_w   = (const float*)d_in[9];
    const float* xi_b   = (const float*)d_in[10];
    const float* q_w    = (const float*)d_in[11];
    const float* q_b    = (const float*)d_in[12];
    const float* k_w    = (const float*)d_in[13];
    const float* k_b    = (const float*)d_in[14];
    const float* ca1_w  = (const float*)d_in[15];
    const float* ca1_b  = (const float*)d_in[16];
    const float* ln1_w  = (const float*)d_in[17];
    const float* ln1_b  = (const float*)d_in[18];
    const float* ca2_w  = (const float*)d_in[19];
    const float* ca2_b  = (const float*)d_in[20];
    const float* ln2_w  = (const float*)d_in[21];
    const float* ln2_b  = (const float*)d_in[22];
    float* out = (float*)d_out;
    float* ws  = (float*)d_ws;
    short* At16 = (short*)(ws + WS_AT);
    short* BT  = (short*)(ws + WS_BT);
    short* H   = (short*)(ws + WS_H);

    kBT <<<64, 256, 0, stream>>>(xi_w, BT);
    kA  <<<BB*VV, 256, 0, stream>>>(x, ws + WS_XBAR);
    kH  <<<(BB*TT*VV)/128, 256, 0, stream>>>(x, BT, xi_b, H);
    kB1 <<<BB*VV, 128, 0, stream>>>(ws + WS_XBAR, phi_w, phi_b, th_w, th_b, xi_w, xi_b,
                                    ws + WS_PHIX, ws + WS_THX, ws + WS_HBAR);
    kB2 <<<BB*VV, 128, 0, stream>>>(ws + WS_PHIX, ws + WS_THX, ka_w, ka_b, A, lam, At16);
    kB34<<<BB*VV, 128, 0, stream>>>(At16, ws + WS_HBAR, q_w, q_b, k_w, k_b,
                                    ws + WS_XQ, ws + WS_XK);
    kB5 <<<BB*KK, 64, 0, stream>>>(ws + WS_XQ, ws + WS_XK, ws + WS_HBAR, ws + WS_CA);
    kB6 <<<BB, 128, 0, stream>>>(ws + WS_CA, ca1_w, ca1_b, ln1_w, ln1_b, ca2_w, ca2_b, ws + WS_GATE);
    kZ  <<<BB*(TT/TC)*USP, 128, 0, stream>>>(H, At16, ws + WS_GATE, ln2_w, ln2_b, out);
}

// Round 4
// 474.955 us; speedup vs baseline: 2.6265x; 1.2008x over previous
//
#include <hip/hip_runtime.h>
#include <hip/hip_bf16.h>
#include <math.h>

// Problem constants
#define BB 64
#define TT 128
#define VV 25
#define CC 128
#define KK 128
#define RR 32
#define TG 4    // timesteps per kF block (= waves per block)

typedef __attribute__((ext_vector_type(8))) short bf16x8;
typedef __attribute__((ext_vector_type(4))) float f32x4;

// bf16 helpers (RNE)
static __device__ __forceinline__ short f2bf(float f) {
    union { float f; unsigned u; } a; a.f = f;
    unsigned r = a.u + 0x7fffu + ((a.u >> 16) & 1u);
    return (short)(r >> 16);
}
static __device__ __forceinline__ float bf2f(short s) {
    union { unsigned u; float f; } a; a.u = ((unsigned)(unsigned short)s) << 16;
    return a.f;
}

// Workspace layout (float offsets)
#define WS_XBAR 0              // [B,V,C]      204800
#define WS_PHIX 204800         // [B,V,K]      204800
#define WS_THX  409600         // [B,V,K]      204800
#define WS_HBAR 614400         // [B,V,K]      204800
#define WS_XQ   819200         // [B,V,K]      204800
#define WS_XK   1024000        // [B,V,K]      204800
#define WS_CA   1228800        // [B,K]        8192
#define WS_GATE 1236992        // [B,K]        8192
#define WS_AT   1245184        // [B,V,V,K]    bf16: 5.12M shorts
#define WS_BT   6365184        // [K][C]       16384 bf16 (xi_w transposed)

// ---------------------------------------------------------------------------
// Kernel A: xbar[b,v,c] = mean_t x[b,t,v,c].  One 256-thr block per (b,v) row.
__global__ __launch_bounds__(256) void kA(const float* __restrict__ x, float* __restrict__ xbar) {
    int row = blockIdx.x;                 // b*V + v
    int b = row / VV, v = row % VV;
    int tq = threadIdx.x >> 5, cq = threadIdx.x & 31;
    const float4* x4 = (const float4*)x;
    size_t base = ((size_t)b * TT * VV + v) * 32 + cq;
    float sx = 0.f, sy = 0.f, sz = 0.f, sw = 0.f;
    #pragma unroll 4
    for (int i = 0; i < 16; ++i) {
        float4 a = x4[base + (size_t)(tq * 16 + i) * VV * 32];
        sx += a.x; sy += a.y; sz += a.z; sw += a.w;
    }
    __shared__ float4 red[8][32];
    red[tq][cq] = (float4){sx, sy, sz, sw};
    __syncthreads();
    if (tq == 0) {
        float4 o = red[0][cq];
        #pragma unroll
        for (int j = 1; j < 8; ++j) {
            float4 a = red[j][cq];
            o.x += a.x; o.y += a.y; o.z += a.z; o.w += a.w;
        }
        o.x *= (1.f/TT); o.y *= (1.f/TT); o.z *= (1.f/TT); o.w *= (1.f/TT);
        ((float4*)xbar)[(size_t)row * 32 + cq] = o;
    }
}

// ---------------------------------------------------------------------------
// Kernel BT: BT[n][c] = bf16(xi_w[c][n])
__global__ __launch_bounds__(256) void kBT(const float* __restrict__ xw, short* __restrict__ BT) {
    for (int i = threadIdx.x + blockIdx.x * 256; i < KK * CC; i += 256 * 64) {
        int n = i >> 7, c = i & 127;
        BT[i] = f2bf(xw[c * KK + n]);
    }
}

// ---------------------------------------------------------------------------
// Kernel B1: per (b,v): phi_x / theta_x / Hbar rows from xbar.
__global__ __launch_bounds__(128) void kB1(const float* __restrict__ xbar,
        const float* __restrict__ pw, const float* __restrict__ pb,
        const float* __restrict__ tw, const float* __restrict__ tb,
        const float* __restrict__ xw, const float* __restrict__ xbias,
        float* __restrict__ phix, float* __restrict__ thx, float* __restrict__ hbar) {
    int bv = blockIdx.x;
    int k = threadIdx.x;
    __shared__ float xv[CC];
    xv[k] = xbar[(size_t)bv * CC + k];
    __syncthreads();
    float sp = pb[k], st = tb[k], sh = xbias[k];
    #pragma unroll 4
    for (int c = 0; c < CC; ++c) {
        float xc = xv[c];
        sp = fmaf(xc, pw[c*KK + k], sp);
        st = fmaf(xc, tw[c*KK + k], st);
        sh = fmaf(xc, xw[c*KK + k], sh);
    }
    phix[(size_t)bv*KK + k] = sp;
    thx [(size_t)bv*KK + k] = st;
    hbar[(size_t)bv*KK + k] = sh;
}

// ---------------------------------------------------------------------------
// Kernel B2: per (b,i) block: At16[b,i,j,k] (bf16) for all j.
__global__ __launch_bounds__(128) void kB2(const float* __restrict__ phix, const float* __restrict__ thx,
        const float* __restrict__ kw, const float* __restrict__ kb,
        const float* __restrict__ A, const float* __restrict__ lam,
        short* __restrict__ At16) {
    int bi = blockIdx.x;                 // b*V + i
    int b = bi / VV, i = bi % VV;
    int k = threadIdx.x;
    __shared__ float f[VV][132];
    float ph = phix[((size_t)b*VV + i)*KK + k];
    #pragma unroll 5
    for (int j = 0; j < VV; ++j)
        f[j][k] = tanhf(ph - thx[((size_t)b*VV + j)*KK + k]);
    __syncthreads();
    float s[VV];
    float bias = kb[k];
    #pragma unroll
    for (int j = 0; j < VV; ++j) s[j] = bias;
    #pragma unroll 2
    for (int c = 0; c < CC; c += 4) {
        float w0 = kw[(c+0)*KK + k];
        float w1 = kw[(c+1)*KK + k];
        float w2 = kw[(c+2)*KK + k];
        float w3 = kw[(c+3)*KK + k];
        #pragma unroll
        for (int j = 0; j < VV; ++j) {
            float4 fv = *(const float4*)&f[j][c];
            float t = fmaf(fv.x, w0, fmaf(fv.y, w1, fmaf(fv.z, w2, fv.w * w3)));
            s[j] += t;
        }
    }
    float l = lam[0];
    #pragma unroll 5
    for (int j = 0; j < VV; ++j)
        At16[(((size_t)b*VV + i)*VV + j)*KK + k] = f2bf(A[((size_t)k*VV + i)*VV + j] + l * s[j]);
}

// ---------------------------------------------------------------------------
// Kernel B34: per (b,u): Zbar row (in LDS) then XQ/XK rows.
__global__ __launch_bounds__(128) void kB34(const short* __restrict__ At16, const float* __restrict__ hbar,
        const float* __restrict__ qw, const float* __restrict__ qb,
        const float* __restrict__ kw, const float* __restrict__ kb,
        float* __restrict__ XQ, float* __restrict__ XK) {
    int bu = blockIdx.x;
    int b = bu / VV;
    int k = threadIdx.x;
    __shared__ float zb[132];
    const short* at = At16 + ((size_t)bu * VV) * KK + k;
    const float* hb = hbar + (size_t)b * VV * KK + k;
    float s = 0.f;
    #pragma unroll
    for (int v = 0; v < VV; ++v) s = fmaf(bf2f(at[v*KK]), hb[v*KK], s);
    zb[k] = s;
    __syncthreads();
    float q = qb[k], kk2 = kb[k];
    #pragma unroll 2
    for (int c = 0; c < CC; c += 4) {
        float4 zv = *(const float4*)&zb[c];
        float q0 = qw[(c+0)*KK + k], q1 = qw[(c+1)*KK + k];
        float q2 = qw[(c+2)*KK + k], q3 = qw[(c+3)*KK + k];
        float k0 = kw[(c+0)*KK + k], k1 = kw[(c+1)*KK + k];
        float k2 = kw[(c+2)*KK + k], k3 = kw[(c+3)*KK + k];
        q   = fmaf(zv.x, q0, fmaf(zv.y, q1, fmaf(zv.z, q2, fmaf(zv.w, q3, q))));
        kk2 = fmaf(zv.x, k0, fmaf(zv.y, k1, fmaf(zv.z, k2, fmaf(zv.w, k3, kk2))));
    }
    XQ[(size_t)bu*KK + k] = q;
    XK[(size_t)bu*KK + k] = kk2;
}

// ---------------------------------------------------------------------------
// Kernel B5: ca[b,k] = sum_v Hbar * mean_u softmax_v(q_u k_v / sqrt(T))
__global__ __launch_bounds__(64) void kB5(const float* __restrict__ XQ, const float* __restrict__ XK,
        const float* __restrict__ hbar, float* __restrict__ ca) {
    int b = blockIdx.x >> 7;
    int k = blockIdx.x & 127;
    int tid = threadIdx.x;
    __shared__ float qv[VV], kv[VV], hv[VV], m[VV], dinv[VV];
    if (tid < VV) {
        qv[tid] = XQ[((size_t)b*VV + tid)*KK + k];
        kv[tid] = XK[((size_t)b*VV + tid)*KK + k];
        hv[tid] = hbar[((size_t)b*VV + tid)*KK + k];
    }
    __syncthreads();
    const float invs = 0.08838834764831845f;   // 1/sqrt(128)
    if (tid < VV) {
        float q = qv[tid];
        float mx = -1e30f;
        #pragma unroll
        for (int v = 0; v < VV; ++v) mx = fmaxf(mx, q * kv[v] * invs);
        float d = 0.f;
        #pragma unroll
        for (int v = 0; v < VV; ++v) d += expf(q * kv[v] * invs - mx);
        m[tid] = mx; dinv[tid] = 1.f / d;
    }
    __syncthreads();
    float contrib = 0.f;
    if (tid < VV) {
        float kkv = kv[tid];
        float s = 0.f;
        #pragma unroll
        for (int u = 0; u < VV; ++u) s += expf(qv[u] * kkv * invs - m[u]) * dinv[u];
        contrib = s * (1.f / VV) * hv[tid];
    }
    #pragma unroll
    for (int off = 32; off > 0; off >>= 1) contrib += __shfl_down(contrib, off);
    if (tid == 0) ca[(size_t)b*KK + k] = contrib;
}

// ---------------------------------------------------------------------------
// Kernel B6: gate = sigmoid(gelu(LN(ca@ca1_w+ca1_b)) @ ca2_w + ca2_b)
__global__ __launch_bounds__(128) void kB6(const float* __restrict__ ca,
        const float* __restrict__ w1, const float* __restrict__ b1,
        const float* __restrict__ lw, const float* __restrict__ lb,
        const float* __restrict__ w2, const float* __restrict__ b2,
        float* __restrict__ gate) {
    int b = blockIdx.x;
    int tid = threadIdx.x;
    __shared__ float cas[KK], t1[RR], c1[RR];
    cas[tid] = ca[(size_t)b*KK + tid];
    __syncthreads();
    if (tid < RR) {
        float s = b1[tid];
        for (int c = 0; c < KK; ++c) s = fmaf(cas[c], w1[c*RR + tid], s);
        t1[tid] = s;
    }
    __syncthreads();
    if (tid < RR) {
        float mu = 0.f;
        #pragma unroll
        for (int j = 0; j < RR; ++j) mu += t1[j];
        mu *= (1.f / RR);
        float var = 0.f;
        #pragma unroll
        for (int j = 0; j < RR; ++j) { float d = t1[j] - mu; var = fmaf(d, d, var); }
        var *= (1.f / RR);
        float xn = (t1[tid] - mu) * rsqrtf(var + 1e-5f) * lw[tid] + lb[tid];
        c1[tid] = 0.5f * xn * (1.f + erff(xn * 0.70710678118654752f));
    }
    __syncthreads();
    float g = b2[tid];
    #pragma unroll
    for (int r = 0; r < RR; ++r) g = fmaf(c1[r], w2[r*KK + tid], g);
    gate[(size_t)b*KK + tid] = 1.f / (1.f + expf(-g));
}

// ---------------------------------------------------------------------------
// Kernel F (fused H+Z): block = (b, 4 timesteps), 256 threads / 4 waves.
// Phase 1: wave w computes H[t0+w, v(0..31, clamped), k(0..127)] via MFMA
//          (A-frags converted from global fp32 x, B-frags from bf16 BT),
//          writes bf16 H tile to LDS (pitch 132: quad-stride 264 dw = 8 mod 32
//          -> conflict-free).
// Phase 2: thread (k=tid&127, g=tid>>7) handles tt in {2g,2g+1}:
//          h[tt][v] from LDS; z[tt][u] = gate * sum_v At16[b,u,v,k]*h[tt][v];
//          z overwrites LDS; LN over k per (tt,u); coalesced fp32 stores.
#define HP 132  // LDS row pitch (shorts)
__global__ __launch_bounds__(256, 3) void kF(const float* __restrict__ x,
        const short* __restrict__ BT, const float* __restrict__ xbias,
        const short* __restrict__ At16, const float* __restrict__ gate,
        const float* __restrict__ lw, const float* __restrict__ lb,
        float* __restrict__ out) {
    int b  = blockIdx.x >> 5;         // b-major: 32 consecutive blocks share b (L2 At reuse)
    int tg = blockIdx.x & 31;
    int t0 = tg * TG;
    int tid = threadIdx.x;
    int wave = tid >> 6, lane = tid & 63;
    int l15 = lane & 15, quad = lane >> 4;

    __shared__ short Hs[TG * 32 * HP];      // 33792 B
    __shared__ float ms[TG * 32], rs[TG * 32];

    // ---- Phase 1: MFMA H for timestep t0+wave ----
    {
        const float* xw_base = x + ((size_t)(b * TT + t0 + wave) * VV) * CC;
        f32x4 acc[2][8];
        #pragma unroll
        for (int rt = 0; rt < 2; ++rt)
            #pragma unroll
            for (int ct = 0; ct < 8; ++ct)
                acc[rt][ct] = (f32x4){0.f, 0.f, 0.f, 0.f};

        int va0 = l15;            // rt=0 A-row
        int va1 = 16 + l15;       // rt=1 A-row
        if (va1 > VV - 1) va1 = VV - 1;   // clamp pad rows (results unused)

        #pragma unroll
        for (int s = 0; s < 4; ++s) {
            bf16x8 afr[2];
            #pragma unroll
            for (int rt = 0; rt < 2; ++rt) {
                const float* ap = xw_base + (size_t)(rt ? va1 : va0) * CC + s*32 + quad*8;
                float4 a0 = *(const float4*)ap;
                float4 a1 = *(const float4*)(ap + 4);
                union { bf16x8 v; short h[8]; } u;
                u.h[0] = f2bf(a0.x); u.h[1] = f2bf(a0.y); u.h[2] = f2bf(a0.z); u.h[3] = f2bf(a0.w);
                u.h[4] = f2bf(a1.x); u.h[5] = f2bf(a1.y); u.h[6] = f2bf(a1.z); u.h[7] = f2bf(a1.w);
                afr[rt] = u.v;
            }
            #pragma unroll
            for (int ct = 0; ct < 8; ++ct) {
                bf16x8 bfr = *(const bf16x8*)(BT + (ct*16 + l15) * CC + s*32 + quad*8);
                acc[0][ct] = __builtin_amdgcn_mfma_f32_16x16x32_bf16(afr[0], bfr, acc[0][ct], 0, 0, 0);
                acc[1][ct] = __builtin_amdgcn_mfma_f32_16x16x32_bf16(afr[1], bfr, acc[1][ct], 0, 0, 0);
            }
        }
        // write H tile to LDS: row v = rt*16 + quad*4 + i, col k = ct*16 + l15
        #pragma unroll
        for (int ct = 0; ct < 8; ++ct) {
            float bias = xbias[ct*16 + l15];
            #pragma unroll
            for (int rt = 0; rt < 2; ++rt) {
                int vbase = rt*16 + quad*4;
                #pragma unroll
                for (int i = 0; i < 4; ++i)
                    Hs[(wave*32 + vbase + i) * HP + ct*16 + l15] = f2bf(acc[rt][ct][i] + bias);
            }
        }
    }
    __syncthreads();

    // ---- Phase 2: graph conv + gate ----
    int k = tid & 127, g = tid >> 7;
    int tt0 = 2*g, tt1 = 2*g + 1;

    float h0[VV], h1[VV];
    #pragma unroll
    for (int v = 0; v < VV; ++v) {
        h0[v] = bf2f(Hs[(tt0*32 + v) * HP + k]);
        h1[v] = bf2f(Hs[(tt1*32 + v) * HP + k]);
    }

    float gv = gate[(size_t)b * KK + k];
    const short* atb = At16 + ((size_t)b * VV * VV) * KK + k;
    short z0s[VV], z1s[VV];
    #pragma unroll 1
    for (int u = 0; u < VV; ++u) {
        float z0 = 0.f, z1 = 0.f;
        #pragma unroll
        for (int v = 0; v < VV; ++v) {
            float a = bf2f(atb[(u * VV + v) * KK]);
            z0 = fmaf(a, h0[v], z0);
            z1 = fmaf(a, h1[v], z1);
        }
        z0s[u] = f2bf(z0 * gv);
        z1s[u] = f2bf(z1 * gv);
    }
    __syncthreads();   // all Hs reads done; safe to overwrite with Z

    #pragma unroll
    for (int u = 0; u < VV; ++u) {
        Hs[(tt0*32 + u) * HP + k] = z0s[u];
        Hs[(tt1*32 + u) * HP + k] = z1s[u];
    }
    __syncthreads();

    // ---- LN stats: thread r<128 reduces row (tt=r>>5, u=r&31), u<25 active ----
    if (tid < 128) {
        int u = tid & 31;
        if (u < VV) {
            const short4* zr = (const short4*)(Hs + tid * HP);
            float s = 0.f, s2 = 0.f;
            #pragma unroll 8
            for (int i = 0; i < KK/4; ++i) {
                short4 q = zr[i];
                float a = bf2f(q.x), bq = bf2f(q.y), c = bf2f(q.z), d = bf2f(q.w);
                s += a + bq + c + d;
                s2 = fmaf(a, a, fmaf(bq, bq, fmaf(c, c, fmaf(d, d, s2))));
            }
            float mu = s * (1.f / KK);
            float var = s2 * (1.f / KK) - mu * mu;
            ms[tid] = mu;
            rs[tid] = rsqrtf(var + 1e-5f);
        }
    }
    __syncthreads();

    // ---- epilogue: normalize + affine, coalesced fp32 stores ----
    float w2 = lw[k], b2v = lb[k];
    #pragma unroll 1
    for (int tt = tt0; tt <= tt1; ++tt) {
        float* ob = out + (((size_t)(b * TT + t0 + tt)) * VV) * KK + k;
        #pragma unroll
        for (int u = 0; u < VV; ++u) {
            float val = (bf2f(Hs[(tt*32 + u) * HP + k]) - ms[tt*32 + u]) * rs[tt*32 + u] * w2 + b2v;
            ob[(size_t)u * KK] = val;
        }
    }
}

// ---------------------------------------------------------------------------
extern "C" void kernel_launch(void* const* d_in, const int* in_sizes, int n_in,
                              void* d_out, int out_size, void* d_ws, size_t ws_size,
                              hipStream_t stream) {
    const float* x      = (const float*)d_in[0];
    const float* A      = (const float*)d_in[1];
    const float* lam    = (const float*)d_in[2];
    const float* phi_w  = (const float*)d_in[3];
    const float* phi_b  = (const float*)d_in[4];
    const float* th_w   = (const float*)d_in[5];
    const float* th_b   = (const float*)d_in[6];
    const float* ka_w   = (const float*)d_in[7];
    const float* ka_b   = (const float*)d_in[8];
    const float* xi_w   = (const float*)d_in[9];
    const float* xi_b   = (const float*)d_in[10];
    const float* q_w    = (const float*)d_in[11];
    const float* q_b    = (const float*)d_in[12];
    const float* k_w    = (const float*)d_in[13];
    const float* k_b    = (const float*)d_in[14];
    const float* ca1_w  = (const float*)d_in[15];
    const float* ca1_b  = (const float*)d_in[16];
    const float* ln1_w  = (const float*)d_in[17];
    const float* ln1_b  = (const float*)d_in[18];
    const float* ca2_w  = (const float*)d_in[19];
    const float* ca2_b  = (const float*)d_in[20];
    const float* ln2_w  = (const float*)d_in[21];
    const float* ln2_b  = (const float*)d_in[22];
    float* out = (float*)d_out;
    float* ws  = (float*)d_ws;
    short* At16 = (short*)(ws + WS_AT);
    short* BT  = (short*)(ws + WS_BT);

    kBT <<<64, 256, 0, stream>>>(xi_w, BT);
    kA  <<<BB*VV, 256, 0, stream>>>(x, ws + WS_XBAR);
    kB1 <<<BB*VV, 128, 0, stream>>>(ws + WS_XBAR, phi_w, phi_b, th_w, th_b, xi_w, xi_b,
                                    ws + WS_PHIX, ws + WS_THX, ws + WS_HBAR);
    kB2 <<<BB*VV, 128, 0, stream>>>(ws + WS_PHIX, ws + WS_THX, ka_w, ka_b, A, lam, At16);
    kB34<<<BB*VV, 128, 0, stream>>>(At16, ws + WS_HBAR, q_w, q_b, k_w, k_b,
                                    ws + WS_XQ, ws + WS_XK);
    kB5 <<<BB*KK, 64, 0, stream>>>(ws + WS_XQ, ws + WS_XK, ws + WS_HBAR, ws + WS_CA);
    kB6 <<<BB, 128, 0, stream>>>(ws + WS_CA, ca1_w, ca1_b, ln1_w, ln1_b, ca2_w, ca2_b, ws + WS_GATE);
    kF  <<<BB*(TT/TG), 256, 0, stream>>>(x, BT, xi_b, At16, ws + WS_GATE, ln2_w, ln2_b, out);
}